// Round 2
// baseline (1309.321 us; speedup 1.0000x reference)
//
#include <hip/hip_runtime.h>
#include <cstdint>
#include <cstddef>

// Problem constants
#define BATCH   8
#define KPTS    8192
#define NPT     1024
#define NSAMP   16
#define RAD2    0.09f

typedef float f32x2 __attribute__((ext_vector_type(2)));
typedef float f32x4 __attribute__((ext_vector_type(4)));
typedef short s16x4 __attribute__((ext_vector_type(4)));
typedef short s16x8 __attribute__((ext_vector_type(8)));

// float -> bf16 bits, round-to-nearest-even (data has no NaN).
__device__ __forceinline__ unsigned short f2bf(float x) {
    unsigned u = __float_as_uint(x);
    return (unsigned short)((u + 0x7fffu + ((u >> 16) & 1u)) >> 16);
}

// DPP f32 max step (value-only reduce; lane63 holds wave max after the 6-step chain).
template <int CTRL>
__device__ __forceinline__ float dppmaxf(float v) {
    int o = __builtin_amdgcn_update_dpp(0, __float_as_int(v), CTRL, 0xf, 0xf, true);
    return fmaxf(v, __int_as_float(o));
}

// ---------------------------------------------------------------------------
// Fused FPS + F0 dispatch, 256 threads/block.
// R8: serial-chain cut — no LDS atomic (plain float4 slots {val,x,y,z}, parity
// double-buffered, 1 barrier/iter), winner coords fetched speculatively
// PRE-barrier (overlapped with DPP/ballot) and carried in the slot; post-
// barrier resolve = 4x broadcast b128 reads + 3-compare float tournament
// (strict '>' keeps lower wave => jnp.argmax first-occurrence tie semantics).
// hist written post-barrier by the global winner lane (off the chain).
// ---------------------------------------------------------------------------
__global__ __launch_bounds__(256, 1) void fps_f0_kernel(
    const float* __restrict__ xyz, float* __restrict__ new_xyz,
    const float* __restrict__ feats, const float* __restrict__ w0,
    float* __restrict__ f0out) {
    __shared__ float xs[KPTS], ys[KPTS], zs[KPTS];               // 96 KB (fps)
    __shared__ __align__(16) float4 fslot[2][4];                 // {wmax, x, y, z} per wave
    __shared__ int   hist[NPT + 8];                              // +pad for dead last write
    __shared__ float As[16 * 64];                                // f0 (64-row tile)
    __shared__ float Bs[16 * 130];                               // f0

    const int tid = threadIdx.x;

    if (blockIdx.x >= 8) {
        // ---------------- F0 GEMM: F0[b,p,o] = sum_c feats[b,c,p]*w0[o,3+c]
        // 64-row tiles, 128 blocks/batch, 256 threads (4 rows x 8 cols / thread).
        const int bid = blockIdx.x - 8;
        const int b   = bid >> 7;
        const int p0  = (bid & 127) << 6;
        const int rb  = (tid >> 4) << 2;   // 16 row-groups x 4 rows = 64 rows
        const int ob  = tid & 15;
        const float* fb = feats + (size_t)b * 256 * KPTS;

        float acc[4][8];
#pragma unroll
        for (int r = 0; r < 4; ++r)
#pragma unroll
            for (int c = 0; c < 8; ++c) acc[r][c] = 0.f;

        for (int k0 = 0; k0 < 256; k0 += 16) {
#pragma unroll
            for (int i = 0; i < 4; ++i) {
                int e = tid + (i << 8);        // 0..1023
                int kk = e >> 6, pc = e & 63;
                As[kk * 64 + pc] = fb[(size_t)(k0 + kk) * KPTS + p0 + pc];
            }
#pragma unroll
            for (int i = 0; i < 8; ++i) {
                int e = tid + (i << 8);        // 0..2047
                int o = e >> 4, kk = e & 15;
                Bs[kk * 130 + o] = w0[o * 259 + 3 + k0 + kk];
            }
            __syncthreads();
#pragma unroll
            for (int kk = 0; kk < 16; ++kk) {
                float a[4], wvv[8];
#pragma unroll
                for (int r = 0; r < 4; ++r) a[r] = As[kk * 64 + rb + r];
#pragma unroll
                for (int c = 0; c < 8; ++c) wvv[c] = Bs[kk * 130 + ob + (c << 4)];
#pragma unroll
                for (int r = 0; r < 4; ++r)
#pragma unroll
                    for (int c = 0; c < 8; ++c) acc[r][c] = fmaf(a[r], wvv[c], acc[r][c]);
            }
            __syncthreads();
        }
#pragma unroll
        for (int r = 0; r < 4; ++r) {
            float* outp = f0out + ((size_t)b * KPTS + p0 + rb + r) * 128 + ob;
#pragma unroll
            for (int c = 0; c < 8; ++c) outp[c << 4] = acc[r][c];
        }
        return;
    }

    // ---------------- FPS ----------------
    {
#pragma clang fp contract(off)
        const int b = blockIdx.x;
        const float* xb = xyz + (size_t)b * KPTS * 3;

        for (int i = tid; i < KPTS; i += 256) {
            xs[i] = xb[i * 3 + 0];
            ys[i] = xb[i * 3 + 1];
            zs[i] = xb[i * 3 + 2];
        }
        if (tid == 0) hist[0] = 0;
        __syncthreads();

        const int base = tid << 5;  // 32 points per thread (16 float2 pairs)
        f32x2 px[16], py[16], pz[16], dmn[16];
#pragma unroll
        for (int j = 0; j < 16; ++j) {
            int i0 = base + (j << 1);
            px[j] = (f32x2){xs[i0], xs[i0 + 1]};
            py[j] = (f32x2){ys[i0], ys[i0 + 1]};
            pz[j] = (f32x2){zs[i0], zs[i0 + 1]};
            dmn[j] = (f32x2){1e10f, 1e10f};
        }

        const int w    = tid >> 6;
        const int lane = tid & 63;
        float cx = xs[0], cy = ys[0], cz = zs[0];

        for (int it = 0; it < NPT; ++it) {
            const f32x2 cx2 = (f32x2){cx, cx};
            const f32x2 cy2 = (f32x2){cy, cy};
            const f32x2 cz2 = (f32x2){cz, cz};

            f32x2 mm = (f32x2){-1.0f, -1.0f};
#pragma unroll
            for (int j = 0; j < 16; ++j) {
                f32x2 dx = px[j] - cx2;
                f32x2 dy = py[j] - cy2;
                f32x2 dz = pz[j] - cz2;
                f32x2 d  = (dx * dx + dy * dy) + dz * dz;  // rounded squares, seq adds
                f32x2 nd = __builtin_elementwise_min(dmn[j], d);
                dmn[j] = nd;
                mm = __builtin_elementwise_max(mm, nd);
            }
            float lmax = fmaxf(mm.x, mm.y);

            // Per-lane min matching index (independent of the DPP value chain;
            // the scheduler overlaps the two).
            int ci = 0x7fffffff;
#pragma unroll
            for (int j = 0; j < 16; ++j) {
                if (dmn[j].x == lmax) ci = min(ci, base + (j << 1));
                if (dmn[j].y == lmax) ci = min(ci, base + (j << 1) + 1);
            }
            // Speculative per-lane winner-coord fetch (off the value-critical
            // path; overlaps the DPP chain below). Bit-identical source bits.
            int cic = min(ci, KPTS - 1);
            float xc = xs[cic], yc = ys[cic], zc = zs[cic];

            // f32 value-only wave max (6 dpp+max steps), lane63 valid.
            float wm = lmax;
            wm = dppmaxf<0x111>(wm);
            wm = dppmaxf<0x112>(wm);
            wm = dppmaxf<0x114>(wm);
            wm = dppmaxf<0x118>(wm);
            wm = dppmaxf<0x142>(wm);
            wm = dppmaxf<0x143>(wm);
            float wmax = __int_as_float(
                __builtin_amdgcn_readlane(__float_as_int(wm), 63));

            // fmax returns a bit-identical input, so some lane's lmax == wmax.
            // Ascending lane index ranges -> lowest matching lane = lowest idx.
            unsigned long long mk = __ballot(lmax == wmax);
            int wl = (int)__builtin_ctzll(mk);
            if (lane == wl)
                fslot[it & 1][w] = make_float4(wmax, xc, yc, zc);
            __syncthreads();  // the single barrier (parity dbuf: no reset)

            // Global resolve: broadcast reads + float tournament. Strict '>'
            // keeps the lower wave on value ties (= lower index range), exactly
            // matching jnp.argmax first-occurrence semantics.
            float4 sA = fslot[it & 1][0];
            float4 sB = fslot[it & 1][1];
            float4 sC = fslot[it & 1][2];
            float4 sD = fslot[it & 1][3];
            bool  bAB = sB.x > sA.x;
            float4 U  = bAB ? sB : sA;  int iU = bAB ? 1 : 0;
            bool  bCD = sD.x > sC.x;
            float4 V  = bCD ? sD : sC;  int iV = bCD ? 3 : 2;
            bool  bUV = V.x > U.x;
            float4 F  = bUV ? V : U;    int iW = bUV ? iV : iU;
            cx = F.y; cy = F.z; cz = F.w;
            // hist write by the global winner lane (off the serial chain).
            if (w == iW && lane == wl) hist[it + 1] = ci;
        }

        for (int i = tid; i < NPT; i += 256) {
            int idx = hist[i];
            float* o = new_xyz + ((size_t)b * NPT + i) * 3;
            o[0] = xs[idx]; o[1] = ys[idx]; o[2] = zs[idx];
        }
    }
}

// ---------------------------------------------------------------------------
// Ball query: one wave per query (4 queries / 256-thread block). Verified.
// ---------------------------------------------------------------------------
__global__ __launch_bounds__(256) void ballq_kernel(const float* __restrict__ xyz,
                                                    const float* __restrict__ new_xyz,
                                                    int* __restrict__ idxout) {
    const int tid  = threadIdx.x;
    const int lane = tid & 63;
    const int q    = (blockIdx.x << 2) + (tid >> 6);
    const int b    = q >> 10;
    const float* xb = xyz + (size_t)b * KPTS * 3;
    const float qx = new_xyz[q * 3 + 0];
    const float qy = new_xyz[q * 3 + 1];
    const float qz = new_xyz[q * 3 + 2];
    int* op = idxout + q * NSAMP;

    int total = 0;
    int first_p = 0;
    for (int c = 0; c < KPTS / 64; ++c) {
        int p = (c << 6) + lane;
        float pxv = xb[p * 3 + 0], pyv = xb[p * 3 + 1], pzv = xb[p * 3 + 2];
        float dx = __fsub_rn(qx, pxv), dy = __fsub_rn(qy, pyv), dz = __fsub_rn(qz, pzv);
        float d2 = __fadd_rn(__fadd_rn(__fmul_rn(dx, dx), __fmul_rn(dy, dy)),
                             __fmul_rn(dz, dz));
        bool pred = d2 < RAD2;
        unsigned long long mask = __ballot(pred);
        if (total == 0 && mask != 0ull) first_p = (c << 6) + (int)__builtin_ctzll(mask);
        if (pred) {
            int rank = (int)__popcll(mask & ((1ull << lane) - 1ull));
            int slot = total + rank;
            if (slot < NSAMP) op[slot] = p;
        }
        total += (int)__popcll(mask);
        if (total >= NSAMP) break;
    }
    if (total < NSAMP && lane >= total && lane < NSAMP) op[lane] = first_p;
}

// ---------------------------------------------------------------------------
// MLP via bf16 MFMA. 4 queries (64 rows) per 256-thread block; wave w owns
// query w's 16 rows exclusively (no cross-wave h hazards).
// h, W staged in LDS as bf16, stride 136 (272 B = 17*16: 16B-aligned, no pow2).
// Layers 1,2: D = A*B, A-frag = h[m=lane&15][k=quad*8+j] (b128),
// B-frag = Wsh[n=lane&15 (+16t)][k=quad*8+j] (b128, gemm_bt pattern),
// D: col=lane&15, row=quad*4+reg. fp32 accumulate; BN/ReLU fp32.
// Maxpool entirely in registers (lane-local + 2 shfl_xor). 3 full barriers.
// ---------------------------------------------------------------------------
#define HB 136

__global__ __launch_bounds__(256) void mlp_kernel(
    const float* __restrict__ f0, const int* __restrict__ idxw,
    const float* __restrict__ xyz, const float* __restrict__ new_xyz,
    const float* __restrict__ w0,
    const float* __restrict__ g0, const float* __restrict__ b0,
    const float* __restrict__ m0, const float* __restrict__ v0,
    const float* __restrict__ w1,
    const float* __restrict__ g1, const float* __restrict__ b1a,
    const float* __restrict__ m1, const float* __restrict__ v1,
    const float* __restrict__ w2,
    const float* __restrict__ g2, const float* __restrict__ b2a,
    const float* __restrict__ m2, const float* __restrict__ v2,
    float* __restrict__ featout) {
    const int tid = threadIdx.x;
    const int q0  = blockIdx.x << 2;
    const int b   = q0 >> 10;

    __shared__ __align__(16) unsigned short hbf[64 * HB];    // 17.4 KB
    __shared__ __align__(16) unsigned short Wsh[128 * HB];   // 34.8 KB
    __shared__ float gx[64], gy[64], gz[64];
    __shared__ int   pidx[64];
    __shared__ float s0[128], t0[128], wxs[128], wys[128], wzs[128];
    __shared__ float s1[128], t1[128], s2[128], t2[128];

    if (tid < 64) pidx[tid] = idxw[(q0 + (tid >> 4)) * NSAMP + (tid & 15)];
    if (tid < 128) {
        float sc = g0[tid] / sqrtf(v0[tid] + 1e-5f);
        s0[tid] = sc; t0[tid] = b0[tid] - m0[tid] * sc;
        sc = g1[tid] / sqrtf(v1[tid] + 1e-5f);
        s1[tid] = sc; t1[tid] = b1a[tid] - m1[tid] * sc;
        sc = g2[tid] / sqrtf(v2[tid] + 1e-5f);
        s2[tid] = sc; t2[tid] = b2a[tid] - m2[tid] * sc;
        wxs[tid] = w0[tid * 259 + 0];
        wys[tid] = w0[tid * 259 + 1];
        wzs[tid] = w0[tid * 259 + 2];
    }
    __syncthreads();
    if (tid < 64) {
        int p = pidx[tid];
        int q = q0 + (tid >> 4);
        const float* pp = xyz + ((size_t)b * KPTS + p) * 3;
        const float* nq = new_xyz + (size_t)q * 3;
        gx[tid] = (pp[0] - nq[0]) / 0.3f;
        gy[tid] = (pp[1] - nq[1]) / 0.3f;
        gz[tid] = (pp[2] - nq[2]) / 0.3f;
    }
    __syncthreads();

    // Phase A: gather F0 + xyz part + BN0 + ReLU -> hbf (bf16); stage w1 bf16.
#pragma unroll 2
    for (int i = 0; i < 8; ++i) {
        int e = tid + (i << 8);
        int row = e >> 5, o = (e & 31) << 2;
        int p = pidx[row];
        float4 v4 = *(const float4*)(f0 + ((size_t)b * KPTS + p) * 128 + o);
        float gxr = gx[row], gyr = gy[row], gzr = gz[row];
        float r0 = fmaf(wzs[o + 0], gzr, fmaf(wys[o + 0], gyr, fmaf(wxs[o + 0], gxr, v4.x)));
        float r1 = fmaf(wzs[o + 1], gzr, fmaf(wys[o + 1], gyr, fmaf(wxs[o + 1], gxr, v4.y)));
        float r2 = fmaf(wzs[o + 2], gzr, fmaf(wys[o + 2], gyr, fmaf(wxs[o + 2], gxr, v4.z)));
        float r3 = fmaf(wzs[o + 3], gzr, fmaf(wys[o + 3], gyr, fmaf(wxs[o + 3], gxr, v4.w)));
        s16x4 c4;
        c4.x = (short)f2bf(fmaxf(fmaf(r0, s0[o + 0], t0[o + 0]), 0.f));
        c4.y = (short)f2bf(fmaxf(fmaf(r1, s0[o + 1], t0[o + 1]), 0.f));
        c4.z = (short)f2bf(fmaxf(fmaf(r2, s0[o + 2], t0[o + 2]), 0.f));
        c4.w = (short)f2bf(fmaxf(fmaf(r3, s0[o + 3], t0[o + 3]), 0.f));
        *(s16x4*)&hbf[row * HB + o] = c4;
    }
#pragma unroll 4
    for (int i = 0; i < 16; ++i) {
        int e = tid + (i << 8);           // 0..4095
        int o = e >> 5;                    // 0..127
        int kt = (e & 31) << 2;            // 0..124
        float4 w4 = *(const float4*)(w1 + o * 128 + kt);
        s16x4 c4 = { (short)f2bf(w4.x), (short)f2bf(w4.y),
                     (short)f2bf(w4.z), (short)f2bf(w4.w) };
        *(s16x4*)&Wsh[o * HB + kt] = c4;
    }
    __syncthreads();   // barrier 1: hbf + Wsh(w1) ready

    const int w    = tid >> 6;        // wave = query
    const int lane = tid & 63;
    const int l15  = lane & 15;
    const int quad = lane >> 4;
    const int wrow = w << 4;          // this wave's 16 rows

    // ---- Layer 1 MFMA
    f32x4 acc[8];
#pragma unroll
    for (int t = 0; t < 8; ++t) acc[t] = (f32x4){0.f, 0.f, 0.f, 0.f};
#pragma unroll
    for (int k0 = 0; k0 < 128; k0 += 32) {
        s16x8 a = *(const s16x8*)&hbf[(wrow + l15) * HB + k0 + (quad << 3)];
#pragma unroll
        for (int t = 0; t < 8; ++t) {
            s16x8 bf = *(const s16x8*)&Wsh[((t << 4) + l15) * HB + k0 + (quad << 3)];
            acc[t] = __builtin_amdgcn_mfma_f32_16x16x32_bf16(a, bf, acc[t], 0, 0, 0);
        }
    }
    __syncthreads();   // barrier 2: Wsh(w1)/hbf reads done

    // writeback layer1 (bf16, own rows only) + stage w2
#pragma unroll
    for (int t = 0; t < 8; ++t) {
        int o = (t << 4) + l15;
        float ss = s1[o], tt = t1[o];
#pragma unroll
        for (int r = 0; r < 4; ++r) {
            float v = fmaxf(fmaf(acc[t][r], ss, tt), 0.f);
            hbf[(wrow + (quad << 2) + r) * HB + o] = f2bf(v);
        }
    }
#pragma unroll 4
    for (int i = 0; i < 16; ++i) {
        int e = tid + (i << 8);
        int o = e >> 5;
        int kt = (e & 31) << 2;
        float4 w4 = *(const float4*)(w2 + o * 128 + kt);
        s16x4 c4 = { (short)f2bf(w4.x), (short)f2bf(w4.y),
                     (short)f2bf(w4.z), (short)f2bf(w4.w) };
        *(s16x4*)&Wsh[o * HB + kt] = c4;
    }
    __syncthreads();   // barrier 3: hbf(l2 input) + Wsh(w2) ready

    // ---- Layer 2 MFMA
#pragma unroll
    for (int t = 0; t < 8; ++t) acc[t] = (f32x4){0.f, 0.f, 0.f, 0.f};
#pragma unroll
    for (int k0 = 0; k0 < 128; k0 += 32) {
        s16x8 a = *(const s16x8*)&hbf[(wrow + l15) * HB + k0 + (quad << 3)];
#pragma unroll
        for (int t = 0; t < 8; ++t) {
            s16x8 bf = *(const s16x8*)&Wsh[((t << 4) + l15) * HB + k0 + (quad << 3)];
            acc[t] = __builtin_amdgcn_mfma_f32_16x16x32_bf16(a, bf, acc[t], 0, 0, 0);
        }
    }

    // BN2/ReLU + in-register maxpool over the wave's 16 rows (= 1 query)
#pragma unroll
    for (int t = 0; t < 8; ++t) {
        int o = (t << 4) + l15;
        float ss = s2[o], tt = t2[o];
        float m0v = fmaxf(fmaf(acc[t][0], ss, tt), 0.f);
        float m1v = fmaxf(fmaf(acc[t][1], ss, tt), 0.f);
        float m2v = fmaxf(fmaf(acc[t][2], ss, tt), 0.f);
        float m3v = fmaxf(fmaf(acc[t][3], ss, tt), 0.f);
        float m = fmaxf(fmaxf(m0v, m1v), fmaxf(m2v, m3v));
        m = fmaxf(m, __shfl_xor(m, 16));
        m = fmaxf(m, __shfl_xor(m, 32));
        if (quad == 0)
            featout[(size_t)(q0 + w) * 128 + o] = m;
    }
}

// ---------------------------------------------------------------------------
// Head: FC1(bn,relu) -> FC2(bn,relu) -> FC3 + output assembly (fp32, verified).
// ---------------------------------------------------------------------------
__global__ __launch_bounds__(256) void head_kernel(
    const float* __restrict__ feat, const float* __restrict__ new_xyz,
    const float* __restrict__ c1w, const float* __restrict__ c1b,
    const float* __restrict__ c2w, const float* __restrict__ c2b,
    const float* __restrict__ c3w, const float* __restrict__ c3b,
    const float* __restrict__ bg1, const float* __restrict__ bb1,
    const float* __restrict__ bm1, const float* __restrict__ bv1,
    const float* __restrict__ bg2, const float* __restrict__ bb2,
    const float* __restrict__ bm2, const float* __restrict__ bv2,
    const float* __restrict__ msz, float* __restrict__ out) {
    const int tid = threadIdx.x;
    const int q0  = blockIdx.x << 3;
    __shared__ float fs[8][128], n1[8][128], n2[8][128];
    __shared__ float s1[128], t1[128], s2[128], t2[128], ms[54];

#pragma unroll
    for (int i = 0; i < 4; ++i) {
        int e = tid + (i << 8);
        fs[e >> 7][e & 127] = feat[(size_t)q0 * 128 + e];
    }
    if (tid < 128) {
        float sc = bg1[tid] / sqrtf(bv1[tid] + 1e-5f);
        s1[tid] = sc; t1[tid] = bb1[tid] - bm1[tid] * sc;
        sc = bg2[tid] / sqrtf(bv2[tid] + 1e-5f);
        s2[tid] = sc; t2[tid] = bb2[tid] - bm2[tid] * sc;
    }
    if (tid < 54) ms[tid] = msz[tid];
    __syncthreads();

    const int o    = tid & 127;
    const int half = tid >> 7;

    {
        float a[4];
#pragma unroll
        for (int j = 0; j < 4; ++j) a[j] = c1b[o];
        const float* wr = c1w + o * 128;
        for (int k = 0; k < 128; k += 4) {
            float4 w4 = *(const float4*)(wr + k);
#pragma unroll
            for (int j = 0; j < 4; ++j) {
                int qq = half * 4 + j;
                a[j] = fmaf(fs[qq][k + 0], w4.x, a[j]);
                a[j] = fmaf(fs[qq][k + 1], w4.y, a[j]);
                a[j] = fmaf(fs[qq][k + 2], w4.z, a[j]);
                a[j] = fmaf(fs[qq][k + 3], w4.w, a[j]);
            }
        }
#pragma unroll
        for (int j = 0; j < 4; ++j)
            n1[half * 4 + j][o] = fmaxf(fmaf(a[j], s1[o], t1[o]), 0.f);
    }
    __syncthreads();
    {
        float a[4];
#pragma unroll
        for (int j = 0; j < 4; ++j) a[j] = c2b[o];
        const float* wr = c2w + o * 128;
        for (int k = 0; k < 128; k += 4) {
            float4 w4 = *(const float4*)(wr + k);
#pragma unroll
            for (int j = 0; j < 4; ++j) {
                int qq = half * 4 + j;
                a[j] = fmaf(n1[qq][k + 0], w4.x, a[j]);
                a[j] = fmaf(n1[qq][k + 1], w4.y, a[j]);
                a[j] = fmaf(n1[qq][k + 2], w4.z, a[j]);
                a[j] = fmaf(n1[qq][k + 3], w4.w, a[j]);
            }
        }
#pragma unroll
        for (int j = 0; j < 4; ++j)
            n2[half * 4 + j][o] = fmaxf(fmaf(a[j], s2[o], t2[o]), 0.f);
    }
    __syncthreads();
    if (o < 97) {
        float a[4];
#pragma unroll
        for (int j = 0; j < 4; ++j) a[j] = c3b[o];
        const float* wr = c3w + o * 128;
        for (int k = 0; k < 128; k += 4) {
            float4 w4 = *(const float4*)(wr + k);
#pragma unroll
            for (int j = 0; j < 4; ++j) {
                int qq = half * 4 + j;
                a[j] = fmaf(n2[qq][k + 0], w4.x, a[j]);
                a[j] = fmaf(n2[qq][k + 1], w4.y, a[j]);
                a[j] = fmaf(n2[qq][k + 2], w4.z, a[j]);
                a[j] = fmaf(n2[qq][k + 3], w4.w, a[j]);
            }
        }
#pragma unroll
        for (int j = 0; j < 4; ++j) {
            int q = q0 + half * 4 + j;
            float v = a[j];
            if (o >= 2 && o < 5) v += new_xyz[(size_t)q * 3 + (o - 2)];
            else if (o == 6) v *= 3.14159265358979323846f;  // * (pi/NH), NH=1
            else if (o >= 25 && o < 79) v *= ms[o - 25];    // sr * mean_size
            out[(size_t)q * 97 + o] = v;
        }
    }
}

// ---------------------------------------------------------------------------
extern "C" void kernel_launch(void* const* d_in, const int* in_sizes, int n_in,
                              void* d_out, int out_size, void* d_ws, size_t ws_size,
                              hipStream_t stream) {
    const float* xyz      = (const float*)d_in[0];
    const float* features = (const float*)d_in[1];
    const float* w0  = (const float*)d_in[2];
    const float* g0  = (const float*)d_in[3];
    const float* b0  = (const float*)d_in[4];
    const float* m0  = (const float*)d_in[5];
    const float* v0  = (const float*)d_in[6];
    const float* w1  = (const float*)d_in[7];
    const float* g1  = (const float*)d_in[8];
    const float* b1  = (const float*)d_in[9];
    const float* m1  = (const float*)d_in[10];
    const float* v1  = (const float*)d_in[11];
    const float* w2  = (const float*)d_in[12];
    const float* g2  = (const float*)d_in[13];
    const float* b2  = (const float*)d_in[14];
    const float* m2  = (const float*)d_in[15];
    const float* v2  = (const float*)d_in[16];
    const float* c1w = (const float*)d_in[17];
    const float* c1b = (const float*)d_in[18];
    const float* c2w = (const float*)d_in[19];
    const float* c2b = (const float*)d_in[20];
    const float* c3w = (const float*)d_in[21];
    const float* c3b = (const float*)d_in[22];
    const float* bg1 = (const float*)d_in[23];
    const float* bb1 = (const float*)d_in[24];
    const float* bm1 = (const float*)d_in[25];
    const float* bv1 = (const float*)d_in[26];
    const float* bg2 = (const float*)d_in[27];
    const float* bb2 = (const float*)d_in[28];
    const float* bm2 = (const float*)d_in[29];
    const float* bv2 = (const float*)d_in[30];
    const float* msz = (const float*)d_in[31];

    float* F0   = (float*)d_ws;
    float* feat = F0 + (size_t)BATCH * KPTS * 128;
    int*   idxw = (int*)(feat + (size_t)BATCH * NPT * 128);
    float* nxyz = (float*)(idxw + (size_t)BATCH * NPT * NSAMP);
    float* outp = (float*)d_out;

    fps_f0_kernel<<<8 + BATCH * (KPTS / 64), 256, 0, stream>>>(
        xyz, nxyz, features, w0, F0);
    ballq_kernel<<<BATCH * NPT / 4, 256, 0, stream>>>(xyz, nxyz, idxw);
    mlp_kernel  <<<BATCH * NPT / 4, 256, 0, stream>>>(
        F0, idxw, xyz, nxyz, w0, g0, b0, m0, v0,
        w1, g1, b1, m1, v1, w2, g2, b2, m2, v2, feat);
    head_kernel <<<BATCH * NPT / 8, 256, 0, stream>>>(
        feat, nxyz, c1w, c1b, c2w, c2b, c3w, c3b,
        bg1, bb1, bm1, bv1, bg2, bb2, bm2, bv2, msz, outp);
}

// Round 4
// 1258.636 us; speedup vs baseline: 1.0403x; 1.0403x over previous
//
#include <hip/hip_runtime.h>
#include <cstdint>
#include <cstddef>

// Problem constants
#define BATCH   8
#define KPTS    8192
#define NPT     1024
#define NSAMP   16
#define RAD2    0.09f
#define HB      136
#define NWORK   248

typedef float f32x2 __attribute__((ext_vector_type(2)));
typedef float f32x4 __attribute__((ext_vector_type(4)));
typedef short s16x4 __attribute__((ext_vector_type(4)));
typedef short s16x8 __attribute__((ext_vector_type(8)));

// float -> bf16 bits, round-to-nearest-even (data has no NaN).
__device__ __forceinline__ unsigned short f2bf(float x) {
    unsigned u = __float_as_uint(x);
    return (unsigned short)((u + 0x7fffu + ((u >> 16) & 1u)) >> 16);
}

// DPP f32 max step (value-only reduce; lane63 holds wave max after 6 steps).
template <int CTRL>
__device__ __forceinline__ float dppmaxf(float v) {
    int o = __builtin_amdgcn_update_dpp(0, __float_as_int(v), CTRL, 0xf, 0xf, true);
    return fmaxf(v, __int_as_float(o));
}

__device__ __forceinline__ int aload(int* p) {
    return __hip_atomic_load(p, __ATOMIC_ACQUIRE, __HIP_MEMORY_SCOPE_AGENT);
}
__device__ __forceinline__ void abump(int* p, int v) {
    __hip_atomic_fetch_add(p, v, __ATOMIC_RELEASE, __HIP_MEMORY_SCOPE_AGENT);
}

// ---------------------------------------------------------------------------
// Persistent mega-kernel, grid = 256 blocks = CU count (1 block/CU by LDS),
// so ALL blocks are resident simultaneously -> spin gates cannot deadlock
// regardless of dispatch order.
//   blocks 0-7   : FPS producer for batch b (publishes new_xyz in 32-chunks)
//   blocks 8-255 : workers: static F0-GEMM tiles, then static ballq+MLP groups
// cnt[0..7] = published queries per batch; cnt[8] = workers done with GEMM.
// ---------------------------------------------------------------------------
union __align__(16) SM {
    struct {                                            // 102.4 KB
        float xs[KPTS], ys[KPTS], zs[KPTS];
        unsigned long long slot3[3];
        int hist[NPT];
    } fps;
    struct {                                            // 12.4 KB
        float As[16 * 64];
        float Bs[16 * 130];
    } gemm;
    struct {                                            // 92.7 KB
        unsigned short W1[128 * HB];
        unsigned short W2[128 * HB];
        unsigned short hbf[64 * HB];
        float gx[64], gy[64], gz[64];
        int   pidx[64];
        float s0[128], t0[128], wxs[128], wys[128], wzs[128];
        float s1[128], t1[128], s2[128], t2[128];
    } mlp;
};

__global__ __launch_bounds__(256, 1) void mega_kernel(
    const float* __restrict__ xyz, float* __restrict__ new_xyz,
    const float* __restrict__ feats, const float* __restrict__ w0,
    float* __restrict__ f0out,
    const float* __restrict__ g0, const float* __restrict__ b0,
    const float* __restrict__ m0, const float* __restrict__ v0,
    const float* __restrict__ w1,
    const float* __restrict__ g1, const float* __restrict__ b1a,
    const float* __restrict__ m1, const float* __restrict__ v1,
    const float* __restrict__ w2,
    const float* __restrict__ g2, const float* __restrict__ b2a,
    const float* __restrict__ m2, const float* __restrict__ v2,
    float* __restrict__ featout, int* __restrict__ cnt) {
    __shared__ SM sm;
    const int tid = threadIdx.x;
    const int bid = blockIdx.x;

    if (bid < 8) {
        // ---------------- FPS (verified R7 core + chunked publication) -------
#pragma clang fp contract(off)
        const int b = bid;
        const float* xb = xyz + (size_t)b * KPTS * 3;

        for (int i = tid; i < KPTS; i += 256) {
            sm.fps.xs[i] = xb[i * 3 + 0];
            sm.fps.ys[i] = xb[i * 3 + 1];
            sm.fps.zs[i] = xb[i * 3 + 2];
        }
        if (tid < 3) sm.fps.slot3[tid] = 0ull;
        __syncthreads();

        const int base = tid << 5;  // 32 points per thread (16 float2 pairs)
        f32x2 px[16], py[16], pz[16], dmn[16];
#pragma unroll
        for (int j = 0; j < 16; ++j) {
            int i0 = base + (j << 1);
            px[j] = (f32x2){sm.fps.xs[i0], sm.fps.xs[i0 + 1]};
            py[j] = (f32x2){sm.fps.ys[i0], sm.fps.ys[i0 + 1]};
            pz[j] = (f32x2){sm.fps.zs[i0], sm.fps.zs[i0 + 1]};
            dmn[j] = (f32x2){1e10f, 1e10f};
        }

        const int lane = tid & 63;
        int far = 0;
        int cur = 0, nxt = 1;
        for (int it = 0; it < NPT; ++it) {
            if (tid == 0) { sm.fps.hist[it] = far; sm.fps.slot3[nxt] = 0ull; }
            const float cx = sm.fps.xs[far], cy = sm.fps.ys[far], cz = sm.fps.zs[far];
            const f32x2 cx2 = (f32x2){cx, cx};
            const f32x2 cy2 = (f32x2){cy, cy};
            const f32x2 cz2 = (f32x2){cz, cz};

            f32x2 mm = (f32x2){-1.0f, -1.0f};
#pragma unroll
            for (int j = 0; j < 16; ++j) {
                f32x2 dx = px[j] - cx2;
                f32x2 dy = py[j] - cy2;
                f32x2 dz = pz[j] - cz2;
                f32x2 d  = (dx * dx + dy * dy) + dz * dz;  // rounded squares, seq adds
                f32x2 nd = __builtin_elementwise_min(dmn[j], d);
                dmn[j] = nd;
                mm = __builtin_elementwise_max(mm, nd);
            }
            float lmax = fmaxf(mm.x, mm.y);

            int ci = 0x7fffffff;
#pragma unroll
            for (int j = 0; j < 16; ++j) {
                if (dmn[j].x == lmax) ci = min(ci, base + (j << 1));
                if (dmn[j].y == lmax) ci = min(ci, base + (j << 1) + 1);
            }

            float wm = lmax;
            wm = dppmaxf<0x111>(wm);
            wm = dppmaxf<0x112>(wm);
            wm = dppmaxf<0x114>(wm);
            wm = dppmaxf<0x118>(wm);
            wm = dppmaxf<0x142>(wm);
            wm = dppmaxf<0x143>(wm);
            float wmax = __int_as_float(
                __builtin_amdgcn_readlane(__float_as_int(wm), 63));

            unsigned long long mk = __ballot(lmax == wmax);
            int wl = (int)__builtin_ctzll(mk);
            int cw = __builtin_amdgcn_readlane(ci, wl);

            if (lane == 0) {
                unsigned long long pk =
                    ((unsigned long long)__float_as_uint(wmax) << 32)
                    | (unsigned)(8191 - cw);
                atomicMax(&sm.fps.slot3[cur], pk);
            }
            __syncthreads();

            unsigned long long g = sm.fps.slot3[cur];
            far = 8191 - (int)(unsigned)(g & 0xffffffffull);
            cur = nxt;
            nxt = (nxt == 2) ? 0 : nxt + 1;

            // Publish samples (it-31..it) every 32 iterations + release-bump.
            if ((it & 31) == 31) {
                if (tid < 128) {
                    int c = tid & 3;
                    if (c < 3) {
                        int i = (it - 31) + (tid >> 2);
                        int idx = sm.fps.hist[i];
                        float v = (c == 0) ? sm.fps.xs[idx]
                                 : (c == 1) ? sm.fps.ys[idx] : sm.fps.zs[idx];
                        new_xyz[((size_t)b * NPT + i) * 3 + c] = v;
                    }
                }
                __threadfence();
                __syncthreads();
                if (tid == 0) abump(&cnt[b], 32);
            }
        }
        return;
    }

    // ======================= worker (blocks 8-255) ==========================
    const int wk = bid - 8;

    // ---- Phase 1: F0 GEMM, static tiles (1024 x 64-row tiles)
    {
        const int rb = (tid >> 4) << 2;
        const int ob = tid & 15;
        for (int t = wk; t < 1024; t += NWORK) {
            const int b  = t >> 7;
            const int p0 = (t & 127) << 6;
            const float* fb = feats + (size_t)b * 256 * KPTS;

            float acc[4][8];
#pragma unroll
            for (int r = 0; r < 4; ++r)
#pragma unroll
                for (int c = 0; c < 8; ++c) acc[r][c] = 0.f;

            for (int k0 = 0; k0 < 256; k0 += 16) {
#pragma unroll
                for (int i = 0; i < 4; ++i) {
                    int e = tid + (i << 8);
                    int kk = e >> 6, pc = e & 63;
                    sm.gemm.As[kk * 64 + pc] = fb[(size_t)(k0 + kk) * KPTS + p0 + pc];
                }
#pragma unroll
                for (int i = 0; i < 8; ++i) {
                    int e = tid + (i << 8);
                    int o = e >> 4, kk = e & 15;
                    sm.gemm.Bs[kk * 130 + o] = w0[o * 259 + 3 + k0 + kk];
                }
                __syncthreads();
#pragma unroll
                for (int kk = 0; kk < 16; ++kk) {
                    float a[4], wvv[8];
#pragma unroll
                    for (int r = 0; r < 4; ++r) a[r] = sm.gemm.As[kk * 64 + rb + r];
#pragma unroll
                    for (int c = 0; c < 8; ++c) wvv[c] = sm.gemm.Bs[kk * 130 + ob + (c << 4)];
#pragma unroll
                    for (int r = 0; r < 4; ++r)
#pragma unroll
                        for (int c = 0; c < 8; ++c) acc[r][c] = fmaf(a[r], wvv[c], acc[r][c]);
                }
                __syncthreads();
            }
#pragma unroll
            for (int r = 0; r < 4; ++r) {
                float* outp = f0out + ((size_t)b * KPTS + p0 + rb + r) * 128 + ob;
#pragma unroll
                for (int c = 0; c < 8; ++c) outp[c << 4] = acc[r][c];
            }
        }
        __threadfence();
        __syncthreads();
        if (tid == 0) abump(&cnt[8], 1);
    }

    // ---- Phase 2 setup: constants + W1 + W2 staged ONCE per worker
    if (tid < 128) {
        float sc = g0[tid] / sqrtf(v0[tid] + 1e-5f);
        sm.mlp.s0[tid] = sc; sm.mlp.t0[tid] = b0[tid] - m0[tid] * sc;
        sc = g1[tid] / sqrtf(v1[tid] + 1e-5f);
        sm.mlp.s1[tid] = sc; sm.mlp.t1[tid] = b1a[tid] - m1[tid] * sc;
        sc = g2[tid] / sqrtf(v2[tid] + 1e-5f);
        sm.mlp.s2[tid] = sc; sm.mlp.t2[tid] = b2a[tid] - m2[tid] * sc;
        sm.mlp.wxs[tid] = w0[tid * 259 + 0];
        sm.mlp.wys[tid] = w0[tid * 259 + 1];
        sm.mlp.wzs[tid] = w0[tid * 259 + 2];
    }
#pragma unroll 4
    for (int i = 0; i < 16; ++i) {
        int e = tid + (i << 8);
        int o = e >> 5;
        int kt = (e & 31) << 2;
        float4 a4 = *(const float4*)(w1 + o * 128 + kt);
        s16x4 c4 = { (short)f2bf(a4.x), (short)f2bf(a4.y),
                     (short)f2bf(a4.z), (short)f2bf(a4.w) };
        *(s16x4*)&sm.mlp.W1[o * HB + kt] = c4;
        float4 b4 = *(const float4*)(w2 + o * 128 + kt);
        s16x4 d4 = { (short)f2bf(b4.x), (short)f2bf(b4.y),
                     (short)f2bf(b4.z), (short)f2bf(b4.w) };
        *(s16x4*)&sm.mlp.W2[o * HB + kt] = d4;
    }
    __syncthreads();

    const int lane = tid & 63;
    const int w    = tid >> 6;
    const int l15  = lane & 15;
    const int quad = lane >> 4;
    const int wrow = w << 4;

    // ---- Phase 2: consumer groups, static assignment, gated on progress
    for (int g = wk; g < 2048; g += NWORK) {
        const int b  = g & 7;
        const int qg = g >> 3;
        const int q0 = (b << 10) + (qg << 2);

        if (tid == 0) {
            while (aload(&cnt[8]) < NWORK) __builtin_amdgcn_s_sleep(16);
            const int need = (qg << 2) + 4;
            while (aload(&cnt[b]) < need) __builtin_amdgcn_s_sleep(16);
        }
        __syncthreads();   // gate barrier (also isolates per-group LDS reuse)

        // ---- ball query (wave per query), indices into LDS
        {
            const int q = q0 + w;
            const float* xb = xyz + (size_t)b * KPTS * 3;
            const float qx = new_xyz[q * 3 + 0];
            const float qy = new_xyz[q * 3 + 1];
            const float qz = new_xyz[q * 3 + 2];
            int* op = &sm.mlp.pidx[w << 4];

            int total = 0;
            int first_p = 0;
            for (int c = 0; c < KPTS / 64; ++c) {
                int p = (c << 6) + lane;
                float pxv = xb[p * 3 + 0], pyv = xb[p * 3 + 1], pzv = xb[p * 3 + 2];
                float dx = __fsub_rn(qx, pxv), dy = __fsub_rn(qy, pyv), dz = __fsub_rn(qz, pzv);
                float d2 = __fadd_rn(__fadd_rn(__fmul_rn(dx, dx), __fmul_rn(dy, dy)),
                                     __fmul_rn(dz, dz));
                bool pred = d2 < RAD2;
                unsigned long long mask = __ballot(pred);
                if (total == 0 && mask != 0ull) first_p = (c << 6) + (int)__builtin_ctzll(mask);
                if (pred) {
                    int rank = (int)__popcll(mask & ((1ull << lane) - 1ull));
                    int slot = total + rank;
                    if (slot < NSAMP) op[slot] = p;
                }
                total += (int)__popcll(mask);
                if (total >= NSAMP) break;
            }
            if (total < NSAMP && lane >= total && lane < NSAMP) op[lane] = first_p;
        }
        __syncthreads();

        if (tid < 64) {
            int p = sm.mlp.pidx[tid];
            int q = q0 + (tid >> 4);
            const float* pp = xyz + ((size_t)b * KPTS + p) * 3;
            const float* nq = new_xyz + (size_t)q * 3;
            sm.mlp.gx[tid] = (pp[0] - nq[0]) / 0.3f;
            sm.mlp.gy[tid] = (pp[1] - nq[1]) / 0.3f;
            sm.mlp.gz[tid] = (pp[2] - nq[2]) / 0.3f;
        }
        __syncthreads();

        // Phase A: gather F0 + xyz part + BN0 + ReLU -> hbf (bf16)
#pragma unroll 2
        for (int i = 0; i < 8; ++i) {
            int e = tid + (i << 8);
            int row = e >> 5, o = (e & 31) << 2;
            int p = sm.mlp.pidx[row];
            float4 v4 = *(const float4*)(f0out + ((size_t)b * KPTS + p) * 128 + o);
            float gxr = sm.mlp.gx[row], gyr = sm.mlp.gy[row], gzr = sm.mlp.gz[row];
            float r0 = fmaf(sm.mlp.wzs[o + 0], gzr, fmaf(sm.mlp.wys[o + 0], gyr, fmaf(sm.mlp.wxs[o + 0], gxr, v4.x)));
            float r1 = fmaf(sm.mlp.wzs[o + 1], gzr, fmaf(sm.mlp.wys[o + 1], gyr, fmaf(sm.mlp.wxs[o + 1], gxr, v4.y)));
            float r2 = fmaf(sm.mlp.wzs[o + 2], gzr, fmaf(sm.mlp.wys[o + 2], gyr, fmaf(sm.mlp.wxs[o + 2], gxr, v4.z)));
            float r3 = fmaf(sm.mlp.wzs[o + 3], gzr, fmaf(sm.mlp.wys[o + 3], gyr, fmaf(sm.mlp.wxs[o + 3], gxr, v4.w)));
            s16x4 c4;
            c4.x = (short)f2bf(fmaxf(fmaf(r0, sm.mlp.s0[o + 0], sm.mlp.t0[o + 0]), 0.f));
            c4.y = (short)f2bf(fmaxf(fmaf(r1, sm.mlp.s0[o + 1], sm.mlp.t0[o + 1]), 0.f));
            c4.z = (short)f2bf(fmaxf(fmaf(r2, sm.mlp.s0[o + 2], sm.mlp.t0[o + 2]), 0.f));
            c4.w = (short)f2bf(fmaxf(fmaf(r3, sm.mlp.s0[o + 3], sm.mlp.t0[o + 3]), 0.f));
            *(s16x4*)&sm.mlp.hbf[row * HB + o] = c4;
        }
        __syncthreads();   // hbf ready

        // ---- Layer 1 MFMA (W1 resident)
        f32x4 acc[8];
#pragma unroll
        for (int t = 0; t < 8; ++t) acc[t] = (f32x4){0.f, 0.f, 0.f, 0.f};
#pragma unroll
        for (int k0 = 0; k0 < 128; k0 += 32) {
            s16x8 a = *(const s16x8*)&sm.mlp.hbf[(wrow + l15) * HB + k0 + (quad << 3)];
#pragma unroll
            for (int t = 0; t < 8; ++t) {
                s16x8 bf = *(const s16x8*)&sm.mlp.W1[((t << 4) + l15) * HB + k0 + (quad << 3)];
                acc[t] = __builtin_amdgcn_mfma_f32_16x16x32_bf16(a, bf, acc[t], 0, 0, 0);
            }
        }
        __syncthreads();   // hbf reads done

        // writeback layer1 (bf16, own rows only)
#pragma unroll
        for (int t = 0; t < 8; ++t) {
            int o = (t << 4) + l15;
            float ss = sm.mlp.s1[o], tt = sm.mlp.t1[o];
#pragma unroll
            for (int r = 0; r < 4; ++r) {
                float v = fmaxf(fmaf(acc[t][r], ss, tt), 0.f);
                sm.mlp.hbf[(wrow + (quad << 2) + r) * HB + o] = f2bf(v);
            }
        }
        __syncthreads();   // hbf(l2 input) ready

        // ---- Layer 2 MFMA (W2 resident)
#pragma unroll
        for (int t = 0; t < 8; ++t) acc[t] = (f32x4){0.f, 0.f, 0.f, 0.f};
#pragma unroll
        for (int k0 = 0; k0 < 128; k0 += 32) {
            s16x8 a = *(const s16x8*)&sm.mlp.hbf[(wrow + l15) * HB + k0 + (quad << 3)];
#pragma unroll
            for (int t = 0; t < 8; ++t) {
                s16x8 bf = *(const s16x8*)&sm.mlp.W2[((t << 4) + l15) * HB + k0 + (quad << 3)];
                acc[t] = __builtin_amdgcn_mfma_f32_16x16x32_bf16(a, bf, acc[t], 0, 0, 0);
            }
        }

        // BN2/ReLU + in-register maxpool over the wave's 16 rows (= 1 query)
#pragma unroll
        for (int t = 0; t < 8; ++t) {
            int o = (t << 4) + l15;
            float ss = sm.mlp.s2[o], tt = sm.mlp.t2[o];
            float m0v = fmaxf(fmaf(acc[t][0], ss, tt), 0.f);
            float m1v = fmaxf(fmaf(acc[t][1], ss, tt), 0.f);
            float m2v = fmaxf(fmaf(acc[t][2], ss, tt), 0.f);
            float m3v = fmaxf(fmaf(acc[t][3], ss, tt), 0.f);
            float m = fmaxf(fmaxf(m0v, m1v), fmaxf(m2v, m3v));
            m = fmaxf(m, __shfl_xor(m, 16));
            m = fmaxf(m, __shfl_xor(m, 32));
            if (quad == 0)
                featout[(size_t)(q0 + w) * 128 + o] = m;
        }
    }
}

// ---------------------------------------------------------------------------
// Head: FC1(bn,relu) -> FC2(bn,relu) -> FC3 + output assembly (fp32, verified).
// ---------------------------------------------------------------------------
__global__ __launch_bounds__(256) void head_kernel(
    const float* __restrict__ feat, const float* __restrict__ new_xyz,
    const float* __restrict__ c1w, const float* __restrict__ c1b,
    const float* __restrict__ c2w, const float* __restrict__ c2b,
    const float* __restrict__ c3w, const float* __restrict__ c3b,
    const float* __restrict__ bg1, const float* __restrict__ bb1,
    const float* __restrict__ bm1, const float* __restrict__ bv1,
    const float* __restrict__ bg2, const float* __restrict__ bb2,
    const float* __restrict__ bm2, const float* __restrict__ bv2,
    const float* __restrict__ msz, float* __restrict__ out) {
    const int tid = threadIdx.x;
    const int q0  = blockIdx.x << 3;
    __shared__ float fs[8][128], n1[8][128], n2[8][128];
    __shared__ float s1[128], t1[128], s2[128], t2[128], ms[54];

#pragma unroll
    for (int i = 0; i < 4; ++i) {
        int e = tid + (i << 8);
        fs[e >> 7][e & 127] = feat[(size_t)q0 * 128 + e];
    }
    if (tid < 128) {
        float sc = bg1[tid] / sqrtf(bv1[tid] + 1e-5f);
        s1[tid] = sc; t1[tid] = bb1[tid] - bm1[tid] * sc;
        sc = bg2[tid] / sqrtf(bv2[tid] + 1e-5f);
        s2[tid] = sc; t2[tid] = bb2[tid] - bm2[tid] * sc;
    }
    if (tid < 54) ms[tid] = msz[tid];
    __syncthreads();

    const int o    = tid & 127;
    const int half = tid >> 7;

    {
        float a[4];
#pragma unroll
        for (int j = 0; j < 4; ++j) a[j] = c1b[o];
        const float* wr = c1w + o * 128;
        for (int k = 0; k < 128; k += 4) {
            float4 w4 = *(const float4*)(wr + k);
#pragma unroll
            for (int j = 0; j < 4; ++j) {
                int qq = half * 4 + j;
                a[j] = fmaf(fs[qq][k + 0], w4.x, a[j]);
                a[j] = fmaf(fs[qq][k + 1], w4.y, a[j]);
                a[j] = fmaf(fs[qq][k + 2], w4.z, a[j]);
                a[j] = fmaf(fs[qq][k + 3], w4.w, a[j]);
            }
        }
#pragma unroll
        for (int j = 0; j < 4; ++j)
            n1[half * 4 + j][o] = fmaxf(fmaf(a[j], s1[o], t1[o]), 0.f);
    }
    __syncthreads();
    {
        float a[4];
#pragma unroll
        for (int j = 0; j < 4; ++j) a[j] = c2b[o];
        const float* wr = c2w + o * 128;
        for (int k = 0; k < 128; k += 4) {
            float4 w4 = *(const float4*)(wr + k);
#pragma unroll
            for (int j = 0; j < 4; ++j) {
                int qq = half * 4 + j;
                a[j] = fmaf(n1[qq][k + 0], w4.x, a[j]);
                a[j] = fmaf(n1[qq][k + 1], w4.y, a[j]);
                a[j] = fmaf(n1[qq][k + 2], w4.z, a[j]);
                a[j] = fmaf(n1[qq][k + 3], w4.w, a[j]);
            }
        }
#pragma unroll
        for (int j = 0; j < 4; ++j)
            n2[half * 4 + j][o] = fmaxf(fmaf(a[j], s2[o], t2[o]), 0.f);
    }
    __syncthreads();
    if (o < 97) {
        float a[4];
#pragma unroll
        for (int j = 0; j < 4; ++j) a[j] = c3b[o];
        const float* wr = c3w + o * 128;
        for (int k = 0; k < 128; k += 4) {
            float4 w4 = *(const float4*)(wr + k);
#pragma unroll
            for (int j = 0; j < 4; ++j) {
                int qq = half * 4 + j;
                a[j] = fmaf(n2[qq][k + 0], w4.x, a[j]);
                a[j] = fmaf(n2[qq][k + 1], w4.y, a[j]);
                a[j] = fmaf(n2[qq][k + 2], w4.z, a[j]);
                a[j] = fmaf(n2[qq][k + 3], w4.w, a[j]);
            }
        }
#pragma unroll
        for (int j = 0; j < 4; ++j) {
            int q = q0 + half * 4 + j;
            float v = a[j];
            if (o >= 2 && o < 5) v += new_xyz[(size_t)q * 3 + (o - 2)];
            else if (o == 6) v *= 3.14159265358979323846f;  // * (pi/NH), NH=1
            else if (o >= 25 && o < 79) v *= ms[o - 25];    // sr * mean_size
            out[(size_t)q * 97 + o] = v;
        }
    }
}

// ---------------------------------------------------------------------------
extern "C" void kernel_launch(void* const* d_in, const int* in_sizes, int n_in,
                              void* d_out, int out_size, void* d_ws, size_t ws_size,
                              hipStream_t stream) {
    const float* xyz      = (const float*)d_in[0];
    const float* features = (const float*)d_in[1];
    const float* w0  = (const float*)d_in[2];
    const float* g0  = (const float*)d_in[3];
    const float* b0  = (const float*)d_in[4];
    const float* m0  = (const float*)d_in[5];
    const float* v0  = (const float*)d_in[6];
    const float* w1  = (const float*)d_in[7];
    const float* g1  = (const float*)d_in[8];
    const float* b1  = (const float*)d_in[9];
    const float* m1  = (const float*)d_in[10];
    const float* v1  = (const float*)d_in[11];
    const float* w2  = (const float*)d_in[12];
    const float* g2  = (const float*)d_in[13];
    const float* b2  = (const float*)d_in[14];
    const float* m2  = (const float*)d_in[15];
    const float* v2  = (const float*)d_in[16];
    const float* c1w = (const float*)d_in[17];
    const float* c1b = (const float*)d_in[18];
    const float* c2w = (const float*)d_in[19];
    const float* c2b = (const float*)d_in[20];
    const float* c3w = (const float*)d_in[21];
    const float* c3b = (const float*)d_in[22];
    const float* bg1 = (const float*)d_in[23];
    const float* bb1 = (const float*)d_in[24];
    const float* bm1 = (const float*)d_in[25];
    const float* bv1 = (const float*)d_in[26];
    const float* bg2 = (const float*)d_in[27];
    const float* bb2 = (const float*)d_in[28];
    const float* bm2 = (const float*)d_in[29];
    const float* bv2 = (const float*)d_in[30];
    const float* msz = (const float*)d_in[31];

    float* F0   = (float*)d_ws;
    float* feat = F0 + (size_t)BATCH * KPTS * 128;
    int*   cnt  = (int*)(feat + (size_t)BATCH * NPT * 128);   // 16 ints (old idxw slot)
    float* nxyz = (float*)(cnt + (size_t)BATCH * NPT * NSAMP);
    float* outp = (float*)d_out;

    hipMemsetAsync(cnt, 0, 16 * sizeof(int), stream);
    mega_kernel<<<256, 256, 0, stream>>>(
        xyz, nxyz, features, w0, F0,
        g0, b0, m0, v0, w1, g1, b1, m1, v1, w2, g2, b2, m2, v2,
        feat, cnt);
    head_kernel <<<BATCH * NPT / 8, 256, 0, stream>>>(
        feat, nxyz, c1w, c1b, c2w, c2b, c3w, c3b,
        bg1, bb1, bm1, bv1, bg2, bb2, bm2, bv2, msz, outp);
}

// Round 5
// 1200.283 us; speedup vs baseline: 1.0908x; 1.0486x over previous
//
#include <hip/hip_runtime.h>
#include <cstdint>
#include <cstddef>

// Problem constants
#define BATCH   8
#define KPTS    8192
#define NPT     1024
#define NSAMP   16
#define RAD2    0.09f
#define HB      136
#define NWORK   248

typedef float f32x2 __attribute__((ext_vector_type(2)));
typedef float f32x4 __attribute__((ext_vector_type(4)));
typedef short s16x4 __attribute__((ext_vector_type(4)));
typedef short s16x8 __attribute__((ext_vector_type(8)));

// float -> bf16 bits, round-to-nearest-even (data has no NaN).
__device__ __forceinline__ unsigned short f2bf(float x) {
    unsigned u = __float_as_uint(x);
    return (unsigned short)((u + 0x7fffu + ((u >> 16) & 1u)) >> 16);
}

// DPP f32 max step (value-only reduce; lane63 holds wave max after 6 steps).
template <int CTRL>
__device__ __forceinline__ float dppmaxf(float v) {
    int o = __builtin_amdgcn_update_dpp(0, __float_as_int(v), CTRL, 0xf, 0xf, true);
    return fmaxf(v, __int_as_float(o));
}

__device__ __forceinline__ int aload(int* p) {
    return __hip_atomic_load(p, __ATOMIC_ACQUIRE, __HIP_MEMORY_SCOPE_AGENT);
}
__device__ __forceinline__ void abump(int* p, int v) {
    __hip_atomic_fetch_add(p, v, __ATOMIC_RELEASE, __HIP_MEMORY_SCOPE_AGENT);
}

// ---------------------------------------------------------------------------
// Persistent mega-kernel, grid = 256 blocks = CU count (1 block/CU by LDS),
// so ALL blocks are resident simultaneously -> spin gates cannot deadlock
// regardless of dispatch order.
//   blocks 0-7   : FPS producer for batch b (publishes new_xyz in 32-chunks)
//   blocks 8-255 : workers: static F0-GEMM tiles, then static consumer groups
//                  (ballq + MLP + maxpool + FUSED HEAD -> out), gated on cnt.
// cnt[0..7] = published queries per batch; cnt[8] = workers done with GEMM.
// ---------------------------------------------------------------------------
union __align__(16) SM {
    struct {                                            // 102.4 KB (union max)
        float xs[KPTS], ys[KPTS], zs[KPTS];
        unsigned long long slot3[3];
        int hist[NPT];
    } fps;
    struct {                                            // 12.4 KB
        float As[16 * 64];
        float Bs[16 * 130];
    } gemm;
    struct {                                            // ~101 KB
        unsigned short W1[128 * HB];
        unsigned short W2[128 * HB];
        unsigned short hbf[64 * HB];
        float gx[64], gy[64], gz[64];
        int   pidx[64];
        float s0[128], t0[128], wxs[128], wys[128], wzs[128];
        float s1[128], t1[128], s2[128], t2[128];
        float s3[128], t3[128], s4[128], t4[128];       // head BN1 / BN2
        float fs[4][128], n1[4][128], n2[4][128];       // head activations
        float ms[54];
    } mlp;
};

__global__ __launch_bounds__(256, 1) void mega_kernel(
    const float* __restrict__ xyz, float* __restrict__ new_xyz,
    const float* __restrict__ feats, const float* __restrict__ w0,
    float* __restrict__ f0out,
    const float* __restrict__ g0, const float* __restrict__ b0,
    const float* __restrict__ m0, const float* __restrict__ v0,
    const float* __restrict__ w1,
    const float* __restrict__ g1, const float* __restrict__ b1a,
    const float* __restrict__ m1, const float* __restrict__ v1,
    const float* __restrict__ w2,
    const float* __restrict__ g2, const float* __restrict__ b2a,
    const float* __restrict__ m2, const float* __restrict__ v2,
    const float* __restrict__ c1w, const float* __restrict__ c1b,
    const float* __restrict__ c2w, const float* __restrict__ c2b,
    const float* __restrict__ c3w, const float* __restrict__ c3b,
    const float* __restrict__ bg1, const float* __restrict__ bb1,
    const float* __restrict__ bm1, const float* __restrict__ bv1,
    const float* __restrict__ bg2, const float* __restrict__ bb2,
    const float* __restrict__ bm2, const float* __restrict__ bv2,
    const float* __restrict__ msz, float* __restrict__ out,
    int* __restrict__ cnt) {
    __shared__ SM sm;
    const int tid = threadIdx.x;
    const int bid = blockIdx.x;

    if (bid < 8) {
        // ---------------- FPS (verified R7 core + chunked publication) -------
#pragma clang fp contract(off)
        const int b = bid;
        const float* xb = xyz + (size_t)b * KPTS * 3;

        for (int i = tid; i < KPTS; i += 256) {
            sm.fps.xs[i] = xb[i * 3 + 0];
            sm.fps.ys[i] = xb[i * 3 + 1];
            sm.fps.zs[i] = xb[i * 3 + 2];
        }
        if (tid < 3) sm.fps.slot3[tid] = 0ull;
        __syncthreads();

        const int base = tid << 5;  // 32 points per thread (16 float2 pairs)
        f32x2 px[16], py[16], pz[16], dmn[16];
#pragma unroll
        for (int j = 0; j < 16; ++j) {
            int i0 = base + (j << 1);
            px[j] = (f32x2){sm.fps.xs[i0], sm.fps.xs[i0 + 1]};
            py[j] = (f32x2){sm.fps.ys[i0], sm.fps.ys[i0 + 1]};
            pz[j] = (f32x2){sm.fps.zs[i0], sm.fps.zs[i0 + 1]};
            dmn[j] = (f32x2){1e10f, 1e10f};
        }

        const int lane = tid & 63;
        int far = 0;
        int cur = 0, nxt = 1;
        for (int it = 0; it < NPT; ++it) {
            if (tid == 0) { sm.fps.hist[it] = far; sm.fps.slot3[nxt] = 0ull; }
            const float cx = sm.fps.xs[far], cy = sm.fps.ys[far], cz = sm.fps.zs[far];
            const f32x2 cx2 = (f32x2){cx, cx};
            const f32x2 cy2 = (f32x2){cy, cy};
            const f32x2 cz2 = (f32x2){cz, cz};

            f32x2 mm = (f32x2){-1.0f, -1.0f};
#pragma unroll
            for (int j = 0; j < 16; ++j) {
                f32x2 dx = px[j] - cx2;
                f32x2 dy = py[j] - cy2;
                f32x2 dz = pz[j] - cz2;
                f32x2 d  = (dx * dx + dy * dy) + dz * dz;  // rounded squares, seq adds
                f32x2 nd = __builtin_elementwise_min(dmn[j], d);
                dmn[j] = nd;
                mm = __builtin_elementwise_max(mm, nd);
            }
            float lmax = fmaxf(mm.x, mm.y);

            int ci = 0x7fffffff;
#pragma unroll
            for (int j = 0; j < 16; ++j) {
                if (dmn[j].x == lmax) ci = min(ci, base + (j << 1));
                if (dmn[j].y == lmax) ci = min(ci, base + (j << 1) + 1);
            }

            float wm = lmax;
            wm = dppmaxf<0x111>(wm);
            wm = dppmaxf<0x112>(wm);
            wm = dppmaxf<0x114>(wm);
            wm = dppmaxf<0x118>(wm);
            wm = dppmaxf<0x142>(wm);
            wm = dppmaxf<0x143>(wm);
            float wmax = __int_as_float(
                __builtin_amdgcn_readlane(__float_as_int(wm), 63));

            unsigned long long mk = __ballot(lmax == wmax);
            int wl = (int)__builtin_ctzll(mk);
            int cw = __builtin_amdgcn_readlane(ci, wl);

            if (lane == 0) {
                unsigned long long pk =
                    ((unsigned long long)__float_as_uint(wmax) << 32)
                    | (unsigned)(8191 - cw);
                atomicMax(&sm.fps.slot3[cur], pk);
            }
            __syncthreads();

            unsigned long long g = sm.fps.slot3[cur];
            far = 8191 - (int)(unsigned)(g & 0xffffffffull);
            cur = nxt;
            nxt = (nxt == 2) ? 0 : nxt + 1;

            // Publish samples (it-31..it) every 32 iterations + release-bump.
            if ((it & 31) == 31) {
                if (tid < 128) {
                    int c = tid & 3;
                    if (c < 3) {
                        int i = (it - 31) + (tid >> 2);
                        int idx = sm.fps.hist[i];
                        float v = (c == 0) ? sm.fps.xs[idx]
                                 : (c == 1) ? sm.fps.ys[idx] : sm.fps.zs[idx];
                        new_xyz[((size_t)b * NPT + i) * 3 + c] = v;
                    }
                }
                __threadfence();
                __syncthreads();
                if (tid == 0) abump(&cnt[b], 32);
            }
        }
        return;
    }

    // ======================= worker (blocks 8-255) ==========================
    const int wk = bid - 8;

    // ---- Phase 1: F0 GEMM, static tiles (1024 x 64-row tiles)
    {
        const int rb = (tid >> 4) << 2;
        const int ob = tid & 15;
        for (int t = wk; t < 1024; t += NWORK) {
            const int b  = t >> 7;
            const int p0 = (t & 127) << 6;
            const float* fb = feats + (size_t)b * 256 * KPTS;

            float acc[4][8];
#pragma unroll
            for (int r = 0; r < 4; ++r)
#pragma unroll
                for (int c = 0; c < 8; ++c) acc[r][c] = 0.f;

            for (int k0 = 0; k0 < 256; k0 += 16) {
#pragma unroll
                for (int i = 0; i < 4; ++i) {
                    int e = tid + (i << 8);
                    int kk = e >> 6, pc = e & 63;
                    sm.gemm.As[kk * 64 + pc] = fb[(size_t)(k0 + kk) * KPTS + p0 + pc];
                }
#pragma unroll
                for (int i = 0; i < 8; ++i) {
                    int e = tid + (i << 8);
                    int o = e >> 4, kk = e & 15;
                    sm.gemm.Bs[kk * 130 + o] = w0[o * 259 + 3 + k0 + kk];
                }
                __syncthreads();
#pragma unroll
                for (int kk = 0; kk < 16; ++kk) {
                    float a[4], wvv[8];
#pragma unroll
                    for (int r = 0; r < 4; ++r) a[r] = sm.gemm.As[kk * 64 + rb + r];
#pragma unroll
                    for (int c = 0; c < 8; ++c) wvv[c] = sm.gemm.Bs[kk * 130 + ob + (c << 4)];
#pragma unroll
                    for (int r = 0; r < 4; ++r)
#pragma unroll
                        for (int c = 0; c < 8; ++c) acc[r][c] = fmaf(a[r], wvv[c], acc[r][c]);
                }
                __syncthreads();
            }
#pragma unroll
            for (int r = 0; r < 4; ++r) {
                float* outp = f0out + ((size_t)b * KPTS + p0 + rb + r) * 128 + ob;
#pragma unroll
                for (int c = 0; c < 8; ++c) outp[c << 4] = acc[r][c];
            }
        }
        __threadfence();
        __syncthreads();
        if (tid == 0) abump(&cnt[8], 1);
    }

    // ---- Phase 2 setup: constants + W1 + W2 staged ONCE per worker
    if (tid < 128) {
        float sc = g0[tid] / sqrtf(v0[tid] + 1e-5f);
        sm.mlp.s0[tid] = sc; sm.mlp.t0[tid] = b0[tid] - m0[tid] * sc;
        sc = g1[tid] / sqrtf(v1[tid] + 1e-5f);
        sm.mlp.s1[tid] = sc; sm.mlp.t1[tid] = b1a[tid] - m1[tid] * sc;
        sc = g2[tid] / sqrtf(v2[tid] + 1e-5f);
        sm.mlp.s2[tid] = sc; sm.mlp.t2[tid] = b2a[tid] - m2[tid] * sc;
        sc = bg1[tid] / sqrtf(bv1[tid] + 1e-5f);
        sm.mlp.s3[tid] = sc; sm.mlp.t3[tid] = bb1[tid] - bm1[tid] * sc;
        sc = bg2[tid] / sqrtf(bv2[tid] + 1e-5f);
        sm.mlp.s4[tid] = sc; sm.mlp.t4[tid] = bb2[tid] - bm2[tid] * sc;
        sm.mlp.wxs[tid] = w0[tid * 259 + 0];
        sm.mlp.wys[tid] = w0[tid * 259 + 1];
        sm.mlp.wzs[tid] = w0[tid * 259 + 2];
    }
    if (tid < 54) sm.mlp.ms[tid] = msz[tid];
#pragma unroll 4
    for (int i = 0; i < 16; ++i) {
        int e = tid + (i << 8);
        int o = e >> 5;
        int kt = (e & 31) << 2;
        float4 a4 = *(const float4*)(w1 + o * 128 + kt);
        s16x4 c4 = { (short)f2bf(a4.x), (short)f2bf(a4.y),
                     (short)f2bf(a4.z), (short)f2bf(a4.w) };
        *(s16x4*)&sm.mlp.W1[o * HB + kt] = c4;
        float4 b4 = *(const float4*)(w2 + o * 128 + kt);
        s16x4 d4 = { (short)f2bf(b4.x), (short)f2bf(b4.y),
                     (short)f2bf(b4.z), (short)f2bf(b4.w) };
        *(s16x4*)&sm.mlp.W2[o * HB + kt] = d4;
    }
    __syncthreads();

    const int lane = tid & 63;
    const int w    = tid >> 6;
    const int l15  = lane & 15;
    const int quad = lane >> 4;
    const int wrow = w << 4;

    // ---- Phase 2: consumer groups, static assignment, gated on progress
    for (int g = wk; g < 2048; g += NWORK) {
        const int b  = g & 7;
        const int qg = g >> 3;
        const int q0 = (b << 10) + (qg << 2);

        if (tid == 0) {
            while (aload(&cnt[8]) < NWORK) __builtin_amdgcn_s_sleep(16);
            const int need = (qg << 2) + 4;
            while (aload(&cnt[b]) < need) __builtin_amdgcn_s_sleep(16);
        }
        __syncthreads();   // gate barrier (also isolates per-group LDS reuse)

        // ---- ball query (wave per query), indices into LDS
        {
            const int q = q0 + w;
            const float* xb = xyz + (size_t)b * KPTS * 3;
            const float qx = new_xyz[q * 3 + 0];
            const float qy = new_xyz[q * 3 + 1];
            const float qz = new_xyz[q * 3 + 2];
            int* op = &sm.mlp.pidx[w << 4];

            int total = 0;
            int first_p = 0;
            for (int c = 0; c < KPTS / 64; ++c) {
                int p = (c << 6) + lane;
                float pxv = xb[p * 3 + 0], pyv = xb[p * 3 + 1], pzv = xb[p * 3 + 2];
                float dx = __fsub_rn(qx, pxv), dy = __fsub_rn(qy, pyv), dz = __fsub_rn(qz, pzv);
                float d2 = __fadd_rn(__fadd_rn(__fmul_rn(dx, dx), __fmul_rn(dy, dy)),
                                     __fmul_rn(dz, dz));
                bool pred = d2 < RAD2;
                unsigned long long mask = __ballot(pred);
                if (total == 0 && mask != 0ull) first_p = (c << 6) + (int)__builtin_ctzll(mask);
                if (pred) {
                    int rank = (int)__popcll(mask & ((1ull << lane) - 1ull));
                    int slot = total + rank;
                    if (slot < NSAMP) op[slot] = p;
                }
                total += (int)__popcll(mask);
                if (total >= NSAMP) break;
            }
            if (total < NSAMP && lane >= total && lane < NSAMP) op[lane] = first_p;
        }
        __syncthreads();

        if (tid < 64) {
            int p = sm.mlp.pidx[tid];
            int q = q0 + (tid >> 4);
            const float* pp = xyz + ((size_t)b * KPTS + p) * 3;
            const float* nq = new_xyz + (size_t)q * 3;
            sm.mlp.gx[tid] = (pp[0] - nq[0]) / 0.3f;
            sm.mlp.gy[tid] = (pp[1] - nq[1]) / 0.3f;
            sm.mlp.gz[tid] = (pp[2] - nq[2]) / 0.3f;
        }
        __syncthreads();

        // Phase A: gather F0 + xyz part + BN0 + ReLU -> hbf (bf16)
#pragma unroll 2
        for (int i = 0; i < 8; ++i) {
            int e = tid + (i << 8);
            int row = e >> 5, o = (e & 31) << 2;
            int p = sm.mlp.pidx[row];
            float4 v4 = *(const float4*)(f0out + ((size_t)b * KPTS + p) * 128 + o);
            float gxr = sm.mlp.gx[row], gyr = sm.mlp.gy[row], gzr = sm.mlp.gz[row];
            float r0 = fmaf(sm.mlp.wzs[o + 0], gzr, fmaf(sm.mlp.wys[o + 0], gyr, fmaf(sm.mlp.wxs[o + 0], gxr, v4.x)));
            float r1 = fmaf(sm.mlp.wzs[o + 1], gzr, fmaf(sm.mlp.wys[o + 1], gyr, fmaf(sm.mlp.wxs[o + 1], gxr, v4.y)));
            float r2 = fmaf(sm.mlp.wzs[o + 2], gzr, fmaf(sm.mlp.wys[o + 2], gyr, fmaf(sm.mlp.wxs[o + 2], gxr, v4.z)));
            float r3 = fmaf(sm.mlp.wzs[o + 3], gzr, fmaf(sm.mlp.wys[o + 3], gyr, fmaf(sm.mlp.wxs[o + 3], gxr, v4.w)));
            s16x4 c4;
            c4.x = (short)f2bf(fmaxf(fmaf(r0, sm.mlp.s0[o + 0], sm.mlp.t0[o + 0]), 0.f));
            c4.y = (short)f2bf(fmaxf(fmaf(r1, sm.mlp.s0[o + 1], sm.mlp.t0[o + 1]), 0.f));
            c4.z = (short)f2bf(fmaxf(fmaf(r2, sm.mlp.s0[o + 2], sm.mlp.t0[o + 2]), 0.f));
            c4.w = (short)f2bf(fmaxf(fmaf(r3, sm.mlp.s0[o + 3], sm.mlp.t0[o + 3]), 0.f));
            *(s16x4*)&sm.mlp.hbf[row * HB + o] = c4;
        }
        __syncthreads();   // hbf ready

        // ---- Layer 1 MFMA (W1 resident)
        f32x4 acc[8];
#pragma unroll
        for (int t = 0; t < 8; ++t) acc[t] = (f32x4){0.f, 0.f, 0.f, 0.f};
#pragma unroll
        for (int k0 = 0; k0 < 128; k0 += 32) {
            s16x8 a = *(const s16x8*)&sm.mlp.hbf[(wrow + l15) * HB + k0 + (quad << 3)];
#pragma unroll
            for (int t = 0; t < 8; ++t) {
                s16x8 bf = *(const s16x8*)&sm.mlp.W1[((t << 4) + l15) * HB + k0 + (quad << 3)];
                acc[t] = __builtin_amdgcn_mfma_f32_16x16x32_bf16(a, bf, acc[t], 0, 0, 0);
            }
        }
        __syncthreads();   // hbf reads done

        // writeback layer1 (bf16, own rows only)
#pragma unroll
        for (int t = 0; t < 8; ++t) {
            int o = (t << 4) + l15;
            float ss = sm.mlp.s1[o], tt = sm.mlp.t1[o];
#pragma unroll
            for (int r = 0; r < 4; ++r) {
                float v = fmaxf(fmaf(acc[t][r], ss, tt), 0.f);
                sm.mlp.hbf[(wrow + (quad << 2) + r) * HB + o] = f2bf(v);
            }
        }
        __syncthreads();   // hbf(l2 input) ready

        // ---- Layer 2 MFMA (W2 resident)
#pragma unroll
        for (int t = 0; t < 8; ++t) acc[t] = (f32x4){0.f, 0.f, 0.f, 0.f};
#pragma unroll
        for (int k0 = 0; k0 < 128; k0 += 32) {
            s16x8 a = *(const s16x8*)&sm.mlp.hbf[(wrow + l15) * HB + k0 + (quad << 3)];
#pragma unroll
            for (int t = 0; t < 8; ++t) {
                s16x8 bf = *(const s16x8*)&sm.mlp.W2[((t << 4) + l15) * HB + k0 + (quad << 3)];
                acc[t] = __builtin_amdgcn_mfma_f32_16x16x32_bf16(a, bf, acc[t], 0, 0, 0);
            }
        }

        // BN2/ReLU + in-register maxpool over the wave's 16 rows (= 1 query)
        // -> LDS fs[w][o] (head input; no global round-trip)
#pragma unroll
        for (int t = 0; t < 8; ++t) {
            int o = (t << 4) + l15;
            float ss = sm.mlp.s2[o], tt = sm.mlp.t2[o];
            float m0v = fmaxf(fmaf(acc[t][0], ss, tt), 0.f);
            float m1v = fmaxf(fmaf(acc[t][1], ss, tt), 0.f);
            float m2v = fmaxf(fmaf(acc[t][2], ss, tt), 0.f);
            float m3v = fmaxf(fmaf(acc[t][3], ss, tt), 0.f);
            float m = fmaxf(fmaxf(m0v, m1v), fmaxf(m2v, m3v));
            m = fmaxf(m, __shfl_xor(m, 16));
            m = fmaxf(m, __shfl_xor(m, 32));
            if (quad == 0) sm.mlp.fs[w][o] = m;
        }
        __syncthreads();   // fs ready

        // ---- Fused head (fp32, exact head_kernel math, 2 queries/thread)
        const int o    = tid & 127;
        const int half = tid >> 7;
        {
            float a[2];
#pragma unroll
            for (int j = 0; j < 2; ++j) a[j] = c1b[o];
            const float* wr = c1w + o * 128;
            for (int k = 0; k < 128; k += 4) {
                float4 w4 = *(const float4*)(wr + k);
#pragma unroll
                for (int j = 0; j < 2; ++j) {
                    int qq = half * 2 + j;
                    a[j] = fmaf(sm.mlp.fs[qq][k + 0], w4.x, a[j]);
                    a[j] = fmaf(sm.mlp.fs[qq][k + 1], w4.y, a[j]);
                    a[j] = fmaf(sm.mlp.fs[qq][k + 2], w4.z, a[j]);
                    a[j] = fmaf(sm.mlp.fs[qq][k + 3], w4.w, a[j]);
                }
            }
#pragma unroll
            for (int j = 0; j < 2; ++j)
                sm.mlp.n1[half * 2 + j][o] = fmaxf(fmaf(a[j], sm.mlp.s3[o], sm.mlp.t3[o]), 0.f);
        }
        __syncthreads();
        {
            float a[2];
#pragma unroll
            for (int j = 0; j < 2; ++j) a[j] = c2b[o];
            const float* wr = c2w + o * 128;
            for (int k = 0; k < 128; k += 4) {
                float4 w4 = *(const float4*)(wr + k);
#pragma unroll
                for (int j = 0; j < 2; ++j) {
                    int qq = half * 2 + j;
                    a[j] = fmaf(sm.mlp.n1[qq][k + 0], w4.x, a[j]);
                    a[j] = fmaf(sm.mlp.n1[qq][k + 1], w4.y, a[j]);
                    a[j] = fmaf(sm.mlp.n1[qq][k + 2], w4.z, a[j]);
                    a[j] = fmaf(sm.mlp.n1[qq][k + 3], w4.w, a[j]);
                }
            }
#pragma unroll
            for (int j = 0; j < 2; ++j)
                sm.mlp.n2[half * 2 + j][o] = fmaxf(fmaf(a[j], sm.mlp.s4[o], sm.mlp.t4[o]), 0.f);
        }
        __syncthreads();
        if (o < 97) {
            float a[2];
#pragma unroll
            for (int j = 0; j < 2; ++j) a[j] = c3b[o];
            const float* wr = c3w + o * 128;
            for (int k = 0; k < 128; k += 4) {
                float4 w4 = *(const float4*)(wr + k);
#pragma unroll
                for (int j = 0; j < 2; ++j) {
                    int qq = half * 2 + j;
                    a[j] = fmaf(sm.mlp.n2[qq][k + 0], w4.x, a[j]);
                    a[j] = fmaf(sm.mlp.n2[qq][k + 1], w4.y, a[j]);
                    a[j] = fmaf(sm.mlp.n2[qq][k + 2], w4.z, a[j]);
                    a[j] = fmaf(sm.mlp.n2[qq][k + 3], w4.w, a[j]);
                }
            }
#pragma unroll
            for (int j = 0; j < 2; ++j) {
                int q = q0 + half * 2 + j;
                float v = a[j];
                if (o >= 2 && o < 5) v += new_xyz[(size_t)q * 3 + (o - 2)];
                else if (o == 6) v *= 3.14159265358979323846f;  // * (pi/NH), NH=1
                else if (o >= 25 && o < 79) v *= sm.mlp.ms[o - 25];  // sr * mean_size
                out[(size_t)q * 97 + o] = v;
            }
        }
        __syncthreads();   // n2/fs reads done before next group's reuse
    }
}

// ---------------------------------------------------------------------------
extern "C" void kernel_launch(void* const* d_in, const int* in_sizes, int n_in,
                              void* d_out, int out_size, void* d_ws, size_t ws_size,
                              hipStream_t stream) {
    const float* xyz      = (const float*)d_in[0];
    const float* features = (const float*)d_in[1];
    const float* w0  = (const float*)d_in[2];
    const float* g0  = (const float*)d_in[3];
    const float* b0  = (const float*)d_in[4];
    const float* m0  = (const float*)d_in[5];
    const float* v0  = (const float*)d_in[6];
    const float* w1  = (const float*)d_in[7];
    const float* g1  = (const float*)d_in[8];
    const float* b1  = (const float*)d_in[9];
    const float* m1  = (const float*)d_in[10];
    const float* v1  = (const float*)d_in[11];
    const float* w2  = (const float*)d_in[12];
    const float* g2  = (const float*)d_in[13];
    const float* b2  = (const float*)d_in[14];
    const float* m2  = (const float*)d_in[15];
    const float* v2  = (const float*)d_in[16];
    const float* c1w = (const float*)d_in[17];
    const float* c1b = (const float*)d_in[18];
    const float* c2w = (const float*)d_in[19];
    const float* c2b = (const float*)d_in[20];
    const float* c3w = (const float*)d_in[21];
    const float* c3b = (const float*)d_in[22];
    const float* bg1 = (const float*)d_in[23];
    const float* bb1 = (const float*)d_in[24];
    const float* bm1 = (const float*)d_in[25];
    const float* bv1 = (const float*)d_in[26];
    const float* bg2 = (const float*)d_in[27];
    const float* bb2 = (const float*)d_in[28];
    const float* bm2 = (const float*)d_in[29];
    const float* bv2 = (const float*)d_in[30];
    const float* msz = (const float*)d_in[31];

    float* F0   = (float*)d_ws;
    float* feat = F0 + (size_t)BATCH * KPTS * 128;   // unused (kept layout)
    int*   cnt  = (int*)(feat + (size_t)BATCH * NPT * 128);
    float* nxyz = (float*)(cnt + (size_t)BATCH * NPT * NSAMP);
    float* outp = (float*)d_out;

    hipMemsetAsync(cnt, 0, 16 * sizeof(int), stream);
    mega_kernel<<<256, 256, 0, stream>>>(
        xyz, nxyz, features, w0, F0,
        g0, b0, m0, v0, w1, g1, b1, m1, v1, w2, g2, b2, m2, v2,
        c1w, c1b, c2w, c2b, c3w, c3b,
        bg1, bb1, bm1, bv1, bg2, bb2, bm2, bv2, msz, outp,
        cnt);
}